// Round 12
// baseline (112.024 us; speedup 1.0000x reference)
//
#include <hip/hip_runtime.h>
#include <hip/hip_bf16.h>

// PGExplainer edge mask.  (R12 = R9 structure + Bloom-bitmap prefilter.)
//  1) f12@W1 factorized: P_top = embed@W1[:64]+b1, P_bot = embed@W1[64:]
//     (LDS-tiled fp32 GEMM; k-loop unroll LIMITED to 2 — full unroll
//      spilled to scratch). rowptr + bitmap-zero duties as trailing blocks.
//  2) keys (col*n+row) sorted ascending (np.unique) -> argsort is identity.
//  3) sigmoid(log(u)-log1p(-u)+la) == u / (u + (1-u)*exp(-la)).
//  4) Reverse lookup: 2MB Bloom bitmap over hashed keys (edge_value sets
//     bit(c*n+r) via atomicOr — order-independent => deterministic;
//     symmetrize tests bit(r*n+c)). ~91% of edges confirm absence with ONE
//     L2-resident load; ~9% FPs fall back to exact rowptr + interpolated
//     scan of raw row[]. True reverses ~0.1% gather vals16 q0.16.
//  5) Per-kernel random footprint kept under the 4 MB per-XCD L2
//     (R10 lesson: fusing overflowed L2 -> 87MB HBM fetch, regressed).

typedef __attribute__((ext_vector_type(2))) float f32x2;

#define EPAD 68        // embed-tile row stride (floats)
#define BM_WORDS (1u << 19)   // 2MB bitmap, 2^24 bits
#define HASH_MUL 2654435761u

__global__ __launch_bounds__(256) void precompute_kernel(
        const float* __restrict__ embed,
        const float* __restrict__ W1,
        const float* __restrict__ b1,
        unsigned* __restrict__ Ptop,          // fp8 e4m3, 16 u32 per node
        unsigned* __restrict__ Pbot,
        const int* __restrict__ col,
        int* __restrict__ rowptr,
        unsigned* __restrict__ bitmap,
        int n_nodes, int n_edges, int gemm_blocks, int rp_blocks) {
    int t = threadIdx.x;
    int bid = blockIdx.x;

    if (bid >= gemm_blocks + rp_blocks) {
        // ---- bitmap zero duty: 512 blocks x 256 threads x uint4 ----
        int idx = (bid - gemm_blocks - rp_blocks) * 256 + t;
        if (idx < (int)(BM_WORDS / 4))
            ((uint4*)bitmap)[idx] = make_uint4(0, 0, 0, 0);
        return;
    }
    if (bid >= gemm_blocks) {
        // ---- rowptr duty: rowptr[v] = lower_bound(col, v) ----
        int v = (bid - gemm_blocks) * 256 + t;
        if (v <= n_nodes) {
            int lo = 0, hi = n_edges;
            while (lo < hi) {
                int mid = (lo + hi) >> 1;
                if (col[mid] < v) lo = mid + 1; else hi = mid;
            }
            rowptr[v] = lo;
        }
        return;
    }

    __shared__ float W1s[128 * 64];     // 32 KB
    __shared__ float E[64 * EPAD];      // 17.4 KB
    int base = bid * 64;

#pragma unroll
    for (int i = 0; i < 8; ++i) {
        int idx = i * 256 + t;
        ((float4*)W1s)[idx] = ((const float4*)W1)[idx];
    }
#pragma unroll
    for (int i = 0; i < 4; ++i) {
        int fi = i * 256 + t;
        int n = fi >> 4;
        int k4 = (fi & 15) * 4;
        float4 v;
        if (base + n < n_nodes)
            v = ((const float4*)(embed + (size_t)(base + n) * 64))[fi & 15];
        else
            v = make_float4(0.f, 0.f, 0.f, 0.f);
        *((float4*)(E + n * EPAD + k4)) = v;
    }
    __syncthreads();

    int tj = t & 15, tn = t >> 4;
    int j4 = tj * 4, n4 = tn * 4;
    float4 b1v = *(const float4*)(b1 + j4);
    float4 at[4], ab[4];
#pragma unroll
    for (int i = 0; i < 4; ++i) {
        at[i] = b1v;
        ab[i] = make_float4(0.f, 0.f, 0.f, 0.f);
    }

    // unroll 2 ONLY: full unroll hoists ~768 floats of LDS loads -> spill
#pragma unroll 2
    for (int k4 = 0; k4 < 64; k4 += 4) {
        float4 e[4], wt[4], wb[4];
#pragma unroll
        for (int i = 0; i < 4; ++i) {
            e[i]  = *(const float4*)(E + (n4 + i) * EPAD + k4);
            wt[i] = *(const float4*)(W1s + (k4 + i) * 64 + j4);
            wb[i] = *(const float4*)(W1s + (64 + k4 + i) * 64 + j4);
        }
#pragma unroll
        for (int n = 0; n < 4; ++n) {
#pragma unroll
            for (int kk = 0; kk < 4; ++kk) {
                float ev = (kk == 0) ? e[n].x : (kk == 1) ? e[n].y
                         : (kk == 2) ? e[n].z : e[n].w;
                at[n].x += ev * wt[kk].x;  at[n].y += ev * wt[kk].y;
                at[n].z += ev * wt[kk].z;  at[n].w += ev * wt[kk].w;
                ab[n].x += ev * wb[kk].x;  ab[n].y += ev * wb[kk].y;
                ab[n].z += ev * wb[kk].z;  ab[n].w += ev * wb[kk].w;
            }
        }
    }

#pragma unroll
    for (int i = 0; i < 4; ++i) {
        int node = base + n4 + i;
        if (node >= n_nodes) break;
        int wt8 = __builtin_amdgcn_cvt_pk_fp8_f32(at[i].x, at[i].y, 0, false);
        wt8     = __builtin_amdgcn_cvt_pk_fp8_f32(at[i].z, at[i].w, wt8, true);
        Ptop[(size_t)node * 16 + tj] = (unsigned)wt8;
        int wb8 = __builtin_amdgcn_cvt_pk_fp8_f32(ab[i].x, ab[i].y, 0, false);
        wb8     = __builtin_amdgcn_cvt_pk_fp8_f32(ab[i].z, ab[i].w, wb8, true);
        Pbot[(size_t)node * 16 + tj] = (unsigned)wb8;
    }
}

// 4 relu-dot terms from one fp8-quad word per side, packed f32x2 math
#define DOTW(au, bu, wp, acc0, acc1) do {                             \
    f32x2 alo = __builtin_amdgcn_cvt_pk_f32_fp8((au), false);         \
    f32x2 ahi = __builtin_amdgcn_cvt_pk_f32_fp8((au), true);          \
    f32x2 blo = __builtin_amdgcn_cvt_pk_f32_fp8((bu), false);         \
    f32x2 bhi = __builtin_amdgcn_cvt_pk_f32_fp8((bu), true);          \
    f32x2 s0 = alo + blo, s1 = ahi + bhi;                             \
    s0 = __builtin_elementwise_max(s0, (f32x2)0.f);                   \
    s1 = __builtin_elementwise_max(s1, (f32x2)0.f);                   \
    acc0 += s0 * ((const f32x2*)(wp))[0];                             \
    acc1 += s1 * ((const f32x2*)(wp))[1];                             \
} while (0)

__global__ void edge_value_kernel(const uint4* __restrict__ Ptop,   // fp8x16
                                  const uint4* __restrict__ Pbot,
                                  const float* __restrict__ W2,
                                  const float* __restrict__ b2,
                                  const float* __restrict__ noise,
                                  const int* __restrict__ col,
                                  const int* __restrict__ row,
                                  unsigned short* __restrict__ vals16,
                                  unsigned* __restrict__ bitmap,
                                  int n_edges, unsigned n_nodes) {
    int e = blockIdx.x * blockDim.x + threadIdx.x;
    if (e >= n_edges) return;
    int c = col[e], r = row[e];
    const uint4* pt = Ptop + (size_t)c * 4;
    const uint4* pb = Pbot + (size_t)r * 4;
    f32x2 acc0 = {b2[0], 0.f}, acc1 = {0.f, 0.f};
    f32x2 acc2 = {0.f, 0.f},  acc3 = {0.f, 0.f};
#pragma unroll
    for (int g = 0; g < 4; ++g) {
        uint4 a = pt[g];
        uint4 b = pb[g];
        const float* w = W2 + g * 16;
        DOTW(a.x, b.x, w,      acc0, acc1);
        DOTW(a.y, b.y, w + 4,  acc2, acc3);
        DOTW(a.z, b.z, w + 8,  acc0, acc1);
        DOTW(a.w, b.w, w + 12, acc2, acc3);
    }
    f32x2 acc = (acc0 + acc1) + (acc2 + acc3);
    float la = acc.x + acc.y;
    float u = noise[e];
    float v = u / (u + (1.f - u) * __expf(-la));
    unsigned q = (unsigned)(v * 65535.f + 0.5f);
    if (q > 65535u) q = 65535u;
    vals16[e] = (unsigned short)q;

    // publish own key into the Bloom bitmap (OR is order-independent)
    unsigned k = (unsigned)c * n_nodes + (unsigned)r;
    unsigned h = (k * HASH_MUL) >> 8;            // 24-bit index
    atomicOr(&bitmap[h >> 5], 1u << (h & 31u));
}

// exact scan of raw int32 row within [lo,hi): returns q16 value or 0
__device__ __forceinline__ float rev_scan32(const int* __restrict__ row,
                                            const unsigned short* __restrict__ vals16,
                                            int c, int lo, int hi, int g, int rv) {
    if (rv < c) {
        while (++g < hi) { rv = row[g]; if (rv >= c) break; }
        return (g < hi && rv == c) ? (float)vals16[g] : 0.f;
    } else {
        while (rv > c && g > lo) rv = row[--g];
        return (rv == c) ? (float)vals16[g] : 0.f;
    }
}

__global__ __launch_bounds__(256) void symmetrize_kernel(
        const int* __restrict__ col,
        const int* __restrict__ row,
        const unsigned short* __restrict__ vals16,
        const int* __restrict__ rowptr,
        const unsigned* __restrict__ bitmap,
        float* __restrict__ out,
        int n_edges, unsigned n_nodes, float inv_n) {
    int t = threadIdx.x;
    int e0 = blockIdx.x * 1024 + t;
    int c[4], r[4], lo[4], hi[4], g[4], pr[4];
    unsigned h[4], bw[4];
    float vq[4];
    bool p[4], hit[4], s[4];

    // phase 1: streaming loads (4 edges)
#pragma unroll
    for (int i = 0; i < 4; ++i) {
        int e = e0 + i * 256;
        p[i] = e < n_edges;
        c[i] = 0; r[i] = 0; vq[i] = 0.f;
        if (p[i]) {
            c[i]  = col[e];
            r[i]  = row[e];
            vq[i] = (float)vals16[e];
        }
    }
    // phase 2: bitmap words for the 4 reverse keys (L2-resident 2MB)
#pragma unroll
    for (int i = 0; i < 4; ++i) {
        bw[i] = 0; h[i] = 0;
        if (p[i]) {
            unsigned kq = (unsigned)r[i] * n_nodes + (unsigned)c[i];
            h[i] = (kq * HASH_MUL) >> 8;
            bw[i] = bitmap[h[i] >> 5];
        }
    }
    // phase 3: rowptr pairs, only for bitmap hits (~9%)
#pragma unroll
    for (int i = 0; i < 4; ++i) {
        hit[i] = p[i] && ((bw[i] >> (h[i] & 31u)) & 1u);
        lo[i] = 0; hi[i] = 0;
        if (hit[i]) { lo[i] = rowptr[r[i]]; hi[i] = rowptr[r[i] + 1]; }
    }
    // phase 4: interpolation guesses + initial probes
#pragma unroll
    for (int i = 0; i < 4; ++i) {
        s[i] = hit[i] && hi[i] > lo[i];
        g[i] = 0; pr[i] = 0;
        if (s[i]) {
            g[i] = lo[i] + (int)((float)c[i] * (float)(hi[i] - lo[i]) * inv_n);
            if (g[i] >= hi[i]) g[i] = hi[i] - 1;
            pr[i] = row[g[i]];
        }
    }
    // phase 5: local scans + output
#pragma unroll
    for (int i = 0; i < 4; ++i) {
        if (!p[i]) continue;
        float rev = s[i] ? rev_scan32(row, vals16, c[i], lo[i], hi[i], g[i], pr[i]) : 0.f;
        out[e0 + i * 256] = (vq[i] + rev) * (0.5f / 65535.f);
    }
}

extern "C" void kernel_launch(void* const* d_in, const int* in_sizes, int n_in,
                              void* d_out, int out_size, void* d_ws, size_t ws_size,
                              hipStream_t stream) {
    const float* embed = (const float*)d_in[0];
    const float* W1    = (const float*)d_in[1];
    const float* b1    = (const float*)d_in[2];
    const float* W2    = (const float*)d_in[3];
    const float* b2    = (const float*)d_in[4];
    const float* noise = (const float*)d_in[5];
    const int*   col   = (const int*)d_in[6];
    const int*   row   = (const int*)d_in[7];

    int n_nodes = in_sizes[0] / 64;   // 40000
    int n_edges = in_sizes[5];        // 1600000
    float* out = (float*)d_out;

    char* ws = (char*)d_ws;
    size_t p_sz  = (size_t)n_nodes * 16 * sizeof(unsigned);    // 2.56 MB each
    size_t v_sz  = (size_t)n_edges * sizeof(unsigned short);   // 3.2 MB
    size_t bm_sz = (size_t)BM_WORDS * sizeof(unsigned);        // 2 MB
    unsigned*       Ptop   = (unsigned*)ws;
    unsigned*       Pbot   = (unsigned*)(ws + p_sz);
    unsigned short* vals16 = (unsigned short*)(ws + 2 * p_sz);
    unsigned*       bitmap = (unsigned*)(ws + 2 * p_sz + v_sz);
    int*            rowptr = (int*)(ws + 2 * p_sz + v_sz + bm_sz);

    int gemm_blocks = (n_nodes + 63) / 64;
    int rp_blocks   = (n_nodes + 256) / 256;       // v in [0, n_nodes]
    int bz_blocks   = (int)(BM_WORDS / 4 + 255) / 256;

    precompute_kernel<<<gemm_blocks + rp_blocks + bz_blocks, 256, 0, stream>>>(
        embed, W1, b1, Ptop, Pbot, col, rowptr, bitmap,
        n_nodes, n_edges, gemm_blocks, rp_blocks);

    edge_value_kernel<<<(n_edges + 255) / 256, 256, 0, stream>>>(
        (const uint4*)Ptop, (const uint4*)Pbot, W2, b2, noise, col, row,
        vals16, bitmap, n_edges, (unsigned)n_nodes);

    symmetrize_kernel<<<(n_edges + 1023) / 1024, 256, 0, stream>>>(
        col, row, vals16, rowptr, bitmap, out, n_edges, (unsigned)n_nodes,
        1.0f / (float)n_nodes);
}

// Round 13
// 72.411 us; speedup vs baseline: 1.5471x; 1.5471x over previous
//
#include <hip/hip_runtime.h>
#include <hip/hip_bf16.h>

// PGExplainer edge mask.  (R13 = R9 structure; rowptr duty moved into the
// edge_value launch to hide its dependent-probe latency.
//  FAILED experiments, do not retry: R10 full fusion (random working-set
//  union 8.5MB > 4MB XCD L2 -> 87MB HBM), R11 2-edge/thread edge_value
//  (more per-thread state, no latency win), R12 Bloom atomicOr bitmap
//  (53MB atomic write-back traffic, 66µs edge_value).)
//  1) f12@W1 factorized: P_top = embed@W1[:64]+b1, P_bot = embed@W1[64:]
//     (LDS-tiled fp32 GEMM; k-loop unroll LIMITED to 2 — full unroll
//      spilled to scratch: VGPR=256, 17MB spill traffic).
//  2) keys (col*n+row) sorted ascending (np.unique) -> argsort is identity.
//     Reverse-edge lookup via CSR rowptr + interpolation-guess + local scan.
//  3) sigmoid(log(u)-log1p(-u)+la) == u / (u + (1-u)*exp(-la)).
//  4) Per-kernel random-gather footprint kept under the 4 MB per-XCD L2:
//     - edge_value: Pbot fp8 (2.56 MB random; Ptop streams w/ sorted col)
//     - symmetrize: row16 u16 (3.2 MB probes); vals16 fetched only on match
//  5) symmetrize: 4 edges/thread, 4 independent probe chains interleaved.

typedef __attribute__((ext_vector_type(2))) float f32x2;

#define EPAD 68   // embed-tile row stride (floats): 16B-aligned, bank-spread

__global__ __launch_bounds__(256) void precompute_kernel(
        const float* __restrict__ embed,
        const float* __restrict__ W1,
        const float* __restrict__ b1,
        unsigned* __restrict__ Ptop,          // fp8 e4m3, 16 u32 per node
        unsigned* __restrict__ Pbot,          // fp8 e4m3, 16 u32 per node
        int n_nodes) {
    int t = threadIdx.x;

    __shared__ float W1s[128 * 64];     // 32 KB
    __shared__ float E[64 * EPAD];      // 17.4 KB
    int base = blockIdx.x * 64;

#pragma unroll
    for (int i = 0; i < 8; ++i) {
        int idx = i * 256 + t;
        ((float4*)W1s)[idx] = ((const float4*)W1)[idx];
    }
#pragma unroll
    for (int i = 0; i < 4; ++i) {
        int fi = i * 256 + t;
        int n = fi >> 4;
        int k4 = (fi & 15) * 4;
        float4 v;
        if (base + n < n_nodes)
            v = ((const float4*)(embed + (size_t)(base + n) * 64))[fi & 15];
        else
            v = make_float4(0.f, 0.f, 0.f, 0.f);
        *((float4*)(E + n * EPAD + k4)) = v;
    }
    __syncthreads();

    int tj = t & 15, tn = t >> 4;
    int j4 = tj * 4, n4 = tn * 4;
    float4 b1v = *(const float4*)(b1 + j4);
    float4 at[4], ab[4];
#pragma unroll
    for (int i = 0; i < 4; ++i) {
        at[i] = b1v;
        ab[i] = make_float4(0.f, 0.f, 0.f, 0.f);
    }

    // unroll 2 ONLY: full unroll hoists ~768 floats of LDS loads -> spill
#pragma unroll 2
    for (int k4 = 0; k4 < 64; k4 += 4) {
        float4 e[4], wt[4], wb[4];
#pragma unroll
        for (int i = 0; i < 4; ++i) {
            e[i]  = *(const float4*)(E + (n4 + i) * EPAD + k4);
            wt[i] = *(const float4*)(W1s + (k4 + i) * 64 + j4);
            wb[i] = *(const float4*)(W1s + (64 + k4 + i) * 64 + j4);
        }
#pragma unroll
        for (int n = 0; n < 4; ++n) {
#pragma unroll
            for (int kk = 0; kk < 4; ++kk) {
                float ev = (kk == 0) ? e[n].x : (kk == 1) ? e[n].y
                         : (kk == 2) ? e[n].z : e[n].w;
                at[n].x += ev * wt[kk].x;  at[n].y += ev * wt[kk].y;
                at[n].z += ev * wt[kk].z;  at[n].w += ev * wt[kk].w;
                ab[n].x += ev * wb[kk].x;  ab[n].y += ev * wb[kk].y;
                ab[n].z += ev * wb[kk].z;  ab[n].w += ev * wb[kk].w;
            }
        }
    }

#pragma unroll
    for (int i = 0; i < 4; ++i) {
        int node = base + n4 + i;
        if (node >= n_nodes) break;
        int wt8 = __builtin_amdgcn_cvt_pk_fp8_f32(at[i].x, at[i].y, 0, false);
        wt8     = __builtin_amdgcn_cvt_pk_fp8_f32(at[i].z, at[i].w, wt8, true);
        Ptop[(size_t)node * 16 + tj] = (unsigned)wt8;
        int wb8 = __builtin_amdgcn_cvt_pk_fp8_f32(ab[i].x, ab[i].y, 0, false);
        wb8     = __builtin_amdgcn_cvt_pk_fp8_f32(ab[i].z, ab[i].w, wb8, true);
        Pbot[(size_t)node * 16 + tj] = (unsigned)wb8;
    }
}

// 4 relu-dot terms from one fp8-quad word per side, packed f32x2 math
#define DOTW(au, bu, wp, acc0, acc1) do {                             \
    f32x2 alo = __builtin_amdgcn_cvt_pk_f32_fp8((au), false);         \
    f32x2 ahi = __builtin_amdgcn_cvt_pk_f32_fp8((au), true);          \
    f32x2 blo = __builtin_amdgcn_cvt_pk_f32_fp8((bu), false);         \
    f32x2 bhi = __builtin_amdgcn_cvt_pk_f32_fp8((bu), true);          \
    f32x2 s0 = alo + blo, s1 = ahi + bhi;                             \
    s0 = __builtin_elementwise_max(s0, (f32x2)0.f);                   \
    s1 = __builtin_elementwise_max(s1, (f32x2)0.f);                   \
    acc0 += s0 * ((const f32x2*)(wp))[0];                             \
    acc1 += s1 * ((const f32x2*)(wp))[1];                             \
} while (0)

__global__ __launch_bounds__(256) void edge_value_kernel(
        const uint4* __restrict__ Ptop,   // fp8x16 per node
        const uint4* __restrict__ Pbot,
        const float* __restrict__ W2,
        const float* __restrict__ b2,
        const float* __restrict__ noise,
        const int* __restrict__ col,
        const int* __restrict__ row,
        unsigned short* __restrict__ row16,
        unsigned short* __restrict__ vals16,
        int* __restrict__ rowptr,
        int n_edges, int n_nodes, int rp_blocks) {
    int t = threadIdx.x;
    int bid = blockIdx.x;

    if (bid < rp_blocks) {
        // ---- rowptr duty (consumed only by symmetrize; hides its
        //      dependent-probe latency under this kernel's main body) ----
        int v = bid * 256 + t;
        if (v <= n_nodes) {
            int lo = 0, hi = n_edges;
            while (lo < hi) {
                int mid = (lo + hi) >> 1;
                if (col[mid] < v) lo = mid + 1; else hi = mid;
            }
            rowptr[v] = lo;
        }
        return;
    }

    int e = (bid - rp_blocks) * 256 + t;
    if (e >= n_edges) return;
    int c = col[e], r = row[e];
    const uint4* pt = Ptop + (size_t)c * 4;
    const uint4* pb = Pbot + (size_t)r * 4;
    f32x2 acc0 = {b2[0], 0.f}, acc1 = {0.f, 0.f};
    f32x2 acc2 = {0.f, 0.f},  acc3 = {0.f, 0.f};
#pragma unroll
    for (int g = 0; g < 4; ++g) {
        uint4 a = pt[g];
        uint4 b = pb[g];
        const float* w = W2 + g * 16;
        DOTW(a.x, b.x, w,      acc0, acc1);
        DOTW(a.y, b.y, w + 4,  acc2, acc3);
        DOTW(a.z, b.z, w + 8,  acc0, acc1);
        DOTW(a.w, b.w, w + 12, acc2, acc3);
    }
    f32x2 acc = (acc0 + acc1) + (acc2 + acc3);
    float la = acc.x + acc.y;
    float u = noise[e];
    float v = u / (u + (1.f - u) * __expf(-la));
    unsigned q = (unsigned)(v * 65535.f + 0.5f);
    if (q > 65535u) q = 65535u;
    row16[e]  = (unsigned short)r;
    vals16[e] = (unsigned short)q;
}

// returns q16 value (un-normalized) of reverse edge, or 0
__device__ __forceinline__ float rev_scan(const unsigned short* __restrict__ row16,
                                          const unsigned short* __restrict__ vals16,
                                          int c, int lo, int hi, int g, int rv) {
    if (rv < c) {
        while (++g < hi) { rv = row16[g]; if (rv >= c) break; }
        return (g < hi && rv == c) ? (float)vals16[g] : 0.f;
    } else {
        while (rv > c && g > lo) rv = row16[--g];
        return (rv == c) ? (float)vals16[g] : 0.f;
    }
}

__global__ __launch_bounds__(256) void symmetrize_kernel(
        const int* __restrict__ col,
        const unsigned short* __restrict__ row16,
        const unsigned short* __restrict__ vals16,
        const int* __restrict__ rowptr,
        float* __restrict__ out,
        int n_edges, float inv_n) {
    int t = threadIdx.x;
    int e0 = blockIdx.x * 1024 + t;
    int c[4], r[4], lo[4], hi[4], g[4], pr[4];
    float vq[4];
    bool p[4], s[4];

    // phase 1: streaming loads (4 edges)
#pragma unroll
    for (int i = 0; i < 4; ++i) {
        int e = e0 + i * 256;
        p[i] = e < n_edges;
        c[i] = 0; r[i] = 0; vq[i] = 0.f;
        if (p[i]) {
            c[i]  = col[e];
            r[i]  = row16[e];
            vq[i] = (float)vals16[e];
        }
    }
    // phase 2: rowptr pairs (random 8B in 160KB, L2-resident, 4 issued)
#pragma unroll
    for (int i = 0; i < 4; ++i) {
        lo[i] = 0; hi[i] = 0;
        if (p[i]) { lo[i] = rowptr[r[i]]; hi[i] = rowptr[r[i] + 1]; }
    }
    // phase 3: interpolation guesses + initial probes (4 issued)
#pragma unroll
    for (int i = 0; i < 4; ++i) {
        s[i] = p[i] && hi[i] > lo[i];
        g[i] = 0; pr[i] = 0;
        if (s[i]) {
            g[i] = lo[i] + (int)((float)c[i] * (float)(hi[i] - lo[i]) * inv_n);
            if (g[i] >= hi[i]) g[i] = hi[i] - 1;
            pr[i] = row16[g[i]];
        }
    }
    // phase 4: local scans (same-line L1 hits; value fetched only on match)
#pragma unroll
    for (int i = 0; i < 4; ++i) {
        if (!p[i]) continue;
        float rev = s[i] ? rev_scan(row16, vals16, c[i], lo[i], hi[i], g[i], pr[i]) : 0.f;
        out[e0 + i * 256] = (vq[i] + rev) * (0.5f / 65535.f);
    }
}

extern "C" void kernel_launch(void* const* d_in, const int* in_sizes, int n_in,
                              void* d_out, int out_size, void* d_ws, size_t ws_size,
                              hipStream_t stream) {
    const float* embed = (const float*)d_in[0];
    const float* W1    = (const float*)d_in[1];
    const float* b1    = (const float*)d_in[2];
    const float* W2    = (const float*)d_in[3];
    const float* b2    = (const float*)d_in[4];
    const float* noise = (const float*)d_in[5];
    const int*   col   = (const int*)d_in[6];
    const int*   row   = (const int*)d_in[7];

    int n_nodes = in_sizes[0] / 64;   // 40000
    int n_edges = in_sizes[5];        // 1600000
    float* out = (float*)d_out;

    char* ws = (char*)d_ws;
    size_t p_sz   = (size_t)n_nodes * 16 * sizeof(unsigned);   // 2.56 MB each
    size_t e16_sz = (size_t)n_edges * sizeof(unsigned short);  // 3.2 MB each
    unsigned*       Ptop   = (unsigned*)ws;
    unsigned*       Pbot   = (unsigned*)(ws + p_sz);
    unsigned short* row16  = (unsigned short*)(ws + 2 * p_sz);
    unsigned short* vals16 = (unsigned short*)(ws + 2 * p_sz + e16_sz);
    int*            rowptr = (int*)(ws + 2 * p_sz + 2 * e16_sz);

    int gemm_blocks = (n_nodes + 63) / 64;
    int rp_blocks   = (n_nodes + 256) / 256;   // covers v in [0, n_nodes]

    precompute_kernel<<<gemm_blocks, 256, 0, stream>>>(
        embed, W1, b1, Ptop, Pbot, n_nodes);

    edge_value_kernel<<<rp_blocks + (n_edges + 255) / 256, 256, 0, stream>>>(
        (const uint4*)Ptop, (const uint4*)Pbot, W2, b2, noise, col, row,
        row16, vals16, rowptr, n_edges, n_nodes, rp_blocks);

    symmetrize_kernel<<<(n_edges + 1023) / 1024, 256, 0, stream>>>(
        col, row16, vals16, rowptr, out, n_edges, 1.0f / (float)n_nodes);
}

// Round 14
// 62.621 us; speedup vs baseline: 1.7889x; 1.1563x over previous
//
#include <hip/hip_runtime.h>
#include <hip/hip_bf16.h>

// PGExplainer edge mask.  (R14 = R13 + pair-canonical symmetrize: only the
// c<r side searches; matches (~800 pairs in 1.6M edges) update BOTH outputs
// with disjoint scattered writes. edge_value writes out[e]=0.5*v directly;
// diagonals (c==r) finalized as out=v in edge_value.
//  FAILED experiments, do not retry: R10 full fusion (random working-set
//  union 8.5MB > 4MB XCD L2 -> 87MB HBM), R11 2-edge/thread edge_value,
//  R12 Bloom atomicOr bitmap (53MB atomic write-back, 66µs).)
//  1) f12@W1 factorized: P_top = embed@W1[:64]+b1, P_bot = embed@W1[64:]
//     (LDS-tiled fp32 GEMM; k-loop unroll LIMITED to 2 — full spills).
//  2) keys (col*n+row) sorted ascending (np.unique) -> argsort is identity.
//     Reverse lookup via CSR rowptr + interpolation-guess + local scan.
//  3) sigmoid(log(u)-log1p(-u)+la) == u / (u + (1-u)*exp(-la)).
//  4) Per-kernel random-gather footprint kept under the 4 MB per-XCD L2:
//     - edge_value: Pbot fp8 (2.56 MB random; Ptop streams w/ sorted col)
//     - symmetrize: row16 u16 probes (3.2 MB); vals16 read only on match.

typedef __attribute__((ext_vector_type(2))) float f32x2;

#define EPAD 68   // embed-tile row stride (floats): 16B-aligned, bank-spread

__global__ __launch_bounds__(256) void precompute_kernel(
        const float* __restrict__ embed,
        const float* __restrict__ W1,
        const float* __restrict__ b1,
        unsigned* __restrict__ Ptop,          // fp8 e4m3, 16 u32 per node
        unsigned* __restrict__ Pbot,          // fp8 e4m3, 16 u32 per node
        int n_nodes) {
    int t = threadIdx.x;

    __shared__ float W1s[128 * 64];     // 32 KB
    __shared__ float E[64 * EPAD];      // 17.4 KB
    int base = blockIdx.x * 64;

#pragma unroll
    for (int i = 0; i < 8; ++i) {
        int idx = i * 256 + t;
        ((float4*)W1s)[idx] = ((const float4*)W1)[idx];
    }
#pragma unroll
    for (int i = 0; i < 4; ++i) {
        int fi = i * 256 + t;
        int n = fi >> 4;
        int k4 = (fi & 15) * 4;
        float4 v;
        if (base + n < n_nodes)
            v = ((const float4*)(embed + (size_t)(base + n) * 64))[fi & 15];
        else
            v = make_float4(0.f, 0.f, 0.f, 0.f);
        *((float4*)(E + n * EPAD + k4)) = v;
    }
    __syncthreads();

    int tj = t & 15, tn = t >> 4;
    int j4 = tj * 4, n4 = tn * 4;
    float4 b1v = *(const float4*)(b1 + j4);
    float4 at[4], ab[4];
#pragma unroll
    for (int i = 0; i < 4; ++i) {
        at[i] = b1v;
        ab[i] = make_float4(0.f, 0.f, 0.f, 0.f);
    }

    // unroll 2 ONLY: full unroll hoists ~768 floats of LDS loads -> spill
#pragma unroll 2
    for (int k4 = 0; k4 < 64; k4 += 4) {
        float4 e[4], wt[4], wb[4];
#pragma unroll
        for (int i = 0; i < 4; ++i) {
            e[i]  = *(const float4*)(E + (n4 + i) * EPAD + k4);
            wt[i] = *(const float4*)(W1s + (k4 + i) * 64 + j4);
            wb[i] = *(const float4*)(W1s + (64 + k4 + i) * 64 + j4);
        }
#pragma unroll
        for (int n = 0; n < 4; ++n) {
#pragma unroll
            for (int kk = 0; kk < 4; ++kk) {
                float ev = (kk == 0) ? e[n].x : (kk == 1) ? e[n].y
                         : (kk == 2) ? e[n].z : e[n].w;
                at[n].x += ev * wt[kk].x;  at[n].y += ev * wt[kk].y;
                at[n].z += ev * wt[kk].z;  at[n].w += ev * wt[kk].w;
                ab[n].x += ev * wb[kk].x;  ab[n].y += ev * wb[kk].y;
                ab[n].z += ev * wb[kk].z;  ab[n].w += ev * wb[kk].w;
            }
        }
    }

#pragma unroll
    for (int i = 0; i < 4; ++i) {
        int node = base + n4 + i;
        if (node >= n_nodes) break;
        int wt8 = __builtin_amdgcn_cvt_pk_fp8_f32(at[i].x, at[i].y, 0, false);
        wt8     = __builtin_amdgcn_cvt_pk_fp8_f32(at[i].z, at[i].w, wt8, true);
        Ptop[(size_t)node * 16 + tj] = (unsigned)wt8;
        int wb8 = __builtin_amdgcn_cvt_pk_fp8_f32(ab[i].x, ab[i].y, 0, false);
        wb8     = __builtin_amdgcn_cvt_pk_fp8_f32(ab[i].z, ab[i].w, wb8, true);
        Pbot[(size_t)node * 16 + tj] = (unsigned)wb8;
    }
}

// 4 relu-dot terms from one fp8-quad word per side, packed f32x2 math
#define DOTW(au, bu, wp, acc0, acc1) do {                             \
    f32x2 alo = __builtin_amdgcn_cvt_pk_f32_fp8((au), false);         \
    f32x2 ahi = __builtin_amdgcn_cvt_pk_f32_fp8((au), true);          \
    f32x2 blo = __builtin_amdgcn_cvt_pk_f32_fp8((bu), false);         \
    f32x2 bhi = __builtin_amdgcn_cvt_pk_f32_fp8((bu), true);          \
    f32x2 s0 = alo + blo, s1 = ahi + bhi;                             \
    s0 = __builtin_elementwise_max(s0, (f32x2)0.f);                   \
    s1 = __builtin_elementwise_max(s1, (f32x2)0.f);                   \
    acc0 += s0 * ((const f32x2*)(wp))[0];                             \
    acc1 += s1 * ((const f32x2*)(wp))[1];                             \
} while (0)

__global__ __launch_bounds__(256) void edge_value_kernel(
        const uint4* __restrict__ Ptop,   // fp8x16 per node
        const uint4* __restrict__ Pbot,
        const float* __restrict__ W2,
        const float* __restrict__ b2,
        const float* __restrict__ noise,
        const int* __restrict__ col,
        const int* __restrict__ row,
        unsigned short* __restrict__ row16,
        unsigned short* __restrict__ vals16,
        float* __restrict__ out,
        int* __restrict__ rowptr,
        int n_edges, int n_nodes, int rp_blocks) {
    int t = threadIdx.x;
    int bid = blockIdx.x;

    if (bid < rp_blocks) {
        // ---- rowptr duty (consumed only by symmetrize) ----
        int v = bid * 256 + t;
        if (v <= n_nodes) {
            int lo = 0, hi = n_edges;
            while (lo < hi) {
                int mid = (lo + hi) >> 1;
                if (col[mid] < v) lo = mid + 1; else hi = mid;
            }
            rowptr[v] = lo;
        }
        return;
    }

    int e = (bid - rp_blocks) * 256 + t;
    if (e >= n_edges) return;
    int c = col[e], r = row[e];
    const uint4* pt = Ptop + (size_t)c * 4;
    const uint4* pb = Pbot + (size_t)r * 4;
    f32x2 acc0 = {b2[0], 0.f}, acc1 = {0.f, 0.f};
    f32x2 acc2 = {0.f, 0.f},  acc3 = {0.f, 0.f};
#pragma unroll
    for (int g = 0; g < 4; ++g) {
        uint4 a = pt[g];
        uint4 b = pb[g];
        const float* w = W2 + g * 16;
        DOTW(a.x, b.x, w,      acc0, acc1);
        DOTW(a.y, b.y, w + 4,  acc2, acc3);
        DOTW(a.z, b.z, w + 8,  acc0, acc1);
        DOTW(a.w, b.w, w + 12, acc2, acc3);
    }
    f32x2 acc = (acc0 + acc1) + (acc2 + acc3);
    float la = acc.x + acc.y;
    float u = noise[e];
    float v = u / (u + (1.f - u) * __expf(-la));
    unsigned q = (unsigned)(v * 65535.f + 0.5f);
    if (q > 65535u) q = 65535u;
    row16[e]  = (unsigned short)r;
    vals16[e] = (unsigned short)q;
    // diagonal (c==r) is its own reverse: v_sym = (v+v)/2 = v
    out[e] = (c == r) ? v : 0.5f * v;
}

__global__ __launch_bounds__(256) void symmetrize_kernel(
        const int* __restrict__ col,
        const unsigned short* __restrict__ row16,
        const unsigned short* __restrict__ vals16,
        const int* __restrict__ rowptr,
        float* __restrict__ out,
        int n_edges, float inv_n) {
    int t = threadIdx.x;
    int e0 = blockIdx.x * 1024 + t;
    int c[4], r[4], lo[4], hi[4], g[4], pr[4];
    bool act[4], s[4];

    // phase 1: streaming loads (4 edges); canonical side only (c < r)
#pragma unroll
    for (int i = 0; i < 4; ++i) {
        int e = e0 + i * 256;
        bool p = e < n_edges;
        c[i] = 0; r[i] = -1;
        if (p) { c[i] = col[e]; r[i] = row16[e]; }
        act[i] = p && c[i] < r[i];
    }
    // phase 2: rowptr pairs (random 8B in 160KB, L2-resident)
#pragma unroll
    for (int i = 0; i < 4; ++i) {
        lo[i] = 0; hi[i] = 0;
        if (act[i]) { lo[i] = rowptr[r[i]]; hi[i] = rowptr[r[i] + 1]; }
    }
    // phase 3: interpolation guesses + initial probes
#pragma unroll
    for (int i = 0; i < 4; ++i) {
        s[i] = act[i] && hi[i] > lo[i];
        g[i] = 0; pr[i] = 0;
        if (s[i]) {
            g[i] = lo[i] + (int)((float)c[i] * (float)(hi[i] - lo[i]) * inv_n);
            if (g[i] >= hi[i]) g[i] = hi[i] - 1;
            pr[i] = row16[g[i]];
        }
    }
    // phase 4: local scans; on match (~800 pairs total) update BOTH sides.
    // Pairs are disjoint and edge_value has completed -> race-free.
#pragma unroll
    for (int i = 0; i < 4; ++i) {
        if (!s[i]) continue;
        int gg = g[i], rv = pr[i], hh = hi[i], ll = lo[i], cc = c[i];
        int match = -1;
        if (rv < cc) {
            while (++gg < hh) { rv = row16[gg]; if (rv >= cc) break; }
            if (gg < hh && rv == cc) match = gg;
        } else {
            while (rv > cc && gg > ll) rv = row16[--gg];
            if (rv == cc) match = gg;
        }
        if (match >= 0) {
            int e = e0 + i * 256;
            float theirs = (float)vals16[match] * (0.5f / 65535.f);
            float mine   = (float)vals16[e]     * (0.5f / 65535.f);
            out[e]     += theirs;
            out[match] += mine;
        }
    }
}

extern "C" void kernel_launch(void* const* d_in, const int* in_sizes, int n_in,
                              void* d_out, int out_size, void* d_ws, size_t ws_size,
                              hipStream_t stream) {
    const float* embed = (const float*)d_in[0];
    const float* W1    = (const float*)d_in[1];
    const float* b1    = (const float*)d_in[2];
    const float* W2    = (const float*)d_in[3];
    const float* b2    = (const float*)d_in[4];
    const float* noise = (const float*)d_in[5];
    const int*   col   = (const int*)d_in[6];
    const int*   row   = (const int*)d_in[7];

    int n_nodes = in_sizes[0] / 64;   // 40000
    int n_edges = in_sizes[5];        // 1600000
    float* out = (float*)d_out;

    char* ws = (char*)d_ws;
    size_t p_sz   = (size_t)n_nodes * 16 * sizeof(unsigned);   // 2.56 MB each
    size_t e16_sz = (size_t)n_edges * sizeof(unsigned short);  // 3.2 MB each
    unsigned*       Ptop   = (unsigned*)ws;
    unsigned*       Pbot   = (unsigned*)(ws + p_sz);
    unsigned short* row16  = (unsigned short*)(ws + 2 * p_sz);
    unsigned short* vals16 = (unsigned short*)(ws + 2 * p_sz + e16_sz);
    int*            rowptr = (int*)(ws + 2 * p_sz + 2 * e16_sz);

    int gemm_blocks = (n_nodes + 63) / 64;
    int rp_blocks   = (n_nodes + 256) / 256;   // covers v in [0, n_nodes]

    precompute_kernel<<<gemm_blocks, 256, 0, stream>>>(
        embed, W1, b1, Ptop, Pbot, n_nodes);

    edge_value_kernel<<<rp_blocks + (n_edges + 255) / 256, 256, 0, stream>>>(
        (const uint4*)Ptop, (const uint4*)Pbot, W2, b2, noise, col, row,
        row16, vals16, out, rowptr, n_edges, n_nodes, rp_blocks);

    symmetrize_kernel<<<(n_edges + 1023) / 1024, 256, 0, stream>>>(
        col, row16, vals16, rowptr, out, n_edges, 1.0f / (float)n_nodes);
}

// Round 15
// 61.740 us; speedup vs baseline: 1.8144x; 1.0143x over previous
//
#include <hip/hip_runtime.h>
#include <hip/hip_bf16.h>

// PGExplainer edge mask.  (R15 = R14 minus vals16: matched pairs exchange
// values directly through out[] (fp32-exact; pairs disjoint, canonical c<r
// side does both writes -> race-free, deterministic).
//  FAILED experiments, do not retry: R10 full fusion (random working-set
//  union 8.5MB > 4MB XCD L2 -> 87MB HBM), R11 2-edge/thread edge_value,
//  R12 Bloom atomicOr bitmap (53MB atomic write-back, 66µs).)
//  1) f12@W1 factorized: P_top = embed@W1[:64]+b1, P_bot = embed@W1[64:]
//     (LDS-tiled fp32 GEMM; k-loop unroll LIMITED to 2 — full spills).
//  2) keys (col*n+row) sorted ascending (np.unique) -> argsort is identity.
//     Reverse lookup via CSR rowptr + interpolation-guess + local scan.
//  3) sigmoid(log(u)-log1p(-u)+la) == u / (u + (1-u)*exp(-la)).
//  4) Per-kernel random-gather footprint kept under the 4 MB per-XCD L2:
//     - edge_value: Pbot fp8 (2.56 MB random; Ptop streams w/ sorted col)
//     - symmetrize: row16 u16 probes (3.2 MB); out[] read only on match.

typedef __attribute__((ext_vector_type(2))) float f32x2;

#define EPAD 68   // embed-tile row stride (floats): 16B-aligned, bank-spread

__global__ __launch_bounds__(256) void precompute_kernel(
        const float* __restrict__ embed,
        const float* __restrict__ W1,
        const float* __restrict__ b1,
        unsigned* __restrict__ Ptop,          // fp8 e4m3, 16 u32 per node
        unsigned* __restrict__ Pbot,          // fp8 e4m3, 16 u32 per node
        int n_nodes) {
    int t = threadIdx.x;

    __shared__ float W1s[128 * 64];     // 32 KB
    __shared__ float E[64 * EPAD];      // 17.4 KB
    int base = blockIdx.x * 64;

#pragma unroll
    for (int i = 0; i < 8; ++i) {
        int idx = i * 256 + t;
        ((float4*)W1s)[idx] = ((const float4*)W1)[idx];
    }
#pragma unroll
    for (int i = 0; i < 4; ++i) {
        int fi = i * 256 + t;
        int n = fi >> 4;
        int k4 = (fi & 15) * 4;
        float4 v;
        if (base + n < n_nodes)
            v = ((const float4*)(embed + (size_t)(base + n) * 64))[fi & 15];
        else
            v = make_float4(0.f, 0.f, 0.f, 0.f);
        *((float4*)(E + n * EPAD + k4)) = v;
    }
    __syncthreads();

    int tj = t & 15, tn = t >> 4;
    int j4 = tj * 4, n4 = tn * 4;
    float4 b1v = *(const float4*)(b1 + j4);
    float4 at[4], ab[4];
#pragma unroll
    for (int i = 0; i < 4; ++i) {
        at[i] = b1v;
        ab[i] = make_float4(0.f, 0.f, 0.f, 0.f);
    }

    // unroll 2 ONLY: full unroll hoists ~768 floats of LDS loads -> spill
#pragma unroll 2
    for (int k4 = 0; k4 < 64; k4 += 4) {
        float4 e[4], wt[4], wb[4];
#pragma unroll
        for (int i = 0; i < 4; ++i) {
            e[i]  = *(const float4*)(E + (n4 + i) * EPAD + k4);
            wt[i] = *(const float4*)(W1s + (k4 + i) * 64 + j4);
            wb[i] = *(const float4*)(W1s + (64 + k4 + i) * 64 + j4);
        }
#pragma unroll
        for (int n = 0; n < 4; ++n) {
#pragma unroll
            for (int kk = 0; kk < 4; ++kk) {
                float ev = (kk == 0) ? e[n].x : (kk == 1) ? e[n].y
                         : (kk == 2) ? e[n].z : e[n].w;
                at[n].x += ev * wt[kk].x;  at[n].y += ev * wt[kk].y;
                at[n].z += ev * wt[kk].z;  at[n].w += ev * wt[kk].w;
                ab[n].x += ev * wb[kk].x;  ab[n].y += ev * wb[kk].y;
                ab[n].z += ev * wb[kk].z;  ab[n].w += ev * wb[kk].w;
            }
        }
    }

#pragma unroll
    for (int i = 0; i < 4; ++i) {
        int node = base + n4 + i;
        if (node >= n_nodes) break;
        int wt8 = __builtin_amdgcn_cvt_pk_fp8_f32(at[i].x, at[i].y, 0, false);
        wt8     = __builtin_amdgcn_cvt_pk_fp8_f32(at[i].z, at[i].w, wt8, true);
        Ptop[(size_t)node * 16 + tj] = (unsigned)wt8;
        int wb8 = __builtin_amdgcn_cvt_pk_fp8_f32(ab[i].x, ab[i].y, 0, false);
        wb8     = __builtin_amdgcn_cvt_pk_fp8_f32(ab[i].z, ab[i].w, wb8, true);
        Pbot[(size_t)node * 16 + tj] = (unsigned)wb8;
    }
}

// 4 relu-dot terms from one fp8-quad word per side, packed f32x2 math
#define DOTW(au, bu, wp, acc0, acc1) do {                             \
    f32x2 alo = __builtin_amdgcn_cvt_pk_f32_fp8((au), false);         \
    f32x2 ahi = __builtin_amdgcn_cvt_pk_f32_fp8((au), true);          \
    f32x2 blo = __builtin_amdgcn_cvt_pk_f32_fp8((bu), false);         \
    f32x2 bhi = __builtin_amdgcn_cvt_pk_f32_fp8((bu), true);          \
    f32x2 s0 = alo + blo, s1 = ahi + bhi;                             \
    s0 = __builtin_elementwise_max(s0, (f32x2)0.f);                   \
    s1 = __builtin_elementwise_max(s1, (f32x2)0.f);                   \
    acc0 += s0 * ((const f32x2*)(wp))[0];                             \
    acc1 += s1 * ((const f32x2*)(wp))[1];                             \
} while (0)

__global__ __launch_bounds__(256) void edge_value_kernel(
        const uint4* __restrict__ Ptop,   // fp8x16 per node
        const uint4* __restrict__ Pbot,
        const float* __restrict__ W2,
        const float* __restrict__ b2,
        const float* __restrict__ noise,
        const int* __restrict__ col,
        const int* __restrict__ row,
        unsigned short* __restrict__ row16,
        float* __restrict__ out,
        int* __restrict__ rowptr,
        int n_edges, int n_nodes, int rp_blocks) {
    int t = threadIdx.x;
    int bid = blockIdx.x;

    if (bid < rp_blocks) {
        // ---- rowptr duty (consumed only by symmetrize) ----
        int v = bid * 256 + t;
        if (v <= n_nodes) {
            int lo = 0, hi = n_edges;
            while (lo < hi) {
                int mid = (lo + hi) >> 1;
                if (col[mid] < v) lo = mid + 1; else hi = mid;
            }
            rowptr[v] = lo;
        }
        return;
    }

    int e = (bid - rp_blocks) * 256 + t;
    if (e >= n_edges) return;
    int c = col[e], r = row[e];
    const uint4* pt = Ptop + (size_t)c * 4;
    const uint4* pb = Pbot + (size_t)r * 4;
    f32x2 acc0 = {b2[0], 0.f}, acc1 = {0.f, 0.f};
    f32x2 acc2 = {0.f, 0.f},  acc3 = {0.f, 0.f};
#pragma unroll
    for (int g = 0; g < 4; ++g) {
        uint4 a = pt[g];
        uint4 b = pb[g];
        const float* w = W2 + g * 16;
        DOTW(a.x, b.x, w,      acc0, acc1);
        DOTW(a.y, b.y, w + 4,  acc2, acc3);
        DOTW(a.z, b.z, w + 8,  acc0, acc1);
        DOTW(a.w, b.w, w + 12, acc2, acc3);
    }
    f32x2 acc = (acc0 + acc1) + (acc2 + acc3);
    float la = acc.x + acc.y;
    float u = noise[e];
    float v = u / (u + (1.f - u) * __expf(-la));
    row16[e] = (unsigned short)r;
    // diagonal (c==r) is its own reverse: v_sym = (v+v)/2 = v
    out[e] = (c == r) ? v : 0.5f * v;
}

__global__ __launch_bounds__(256) void symmetrize_kernel(
        const int* __restrict__ col,
        const unsigned short* __restrict__ row16,
        const int* __restrict__ rowptr,
        float* __restrict__ out,
        int n_edges, float inv_n) {
    int t = threadIdx.x;
    int e0 = blockIdx.x * 1024 + t;
    int c[4], r[4], lo[4], hi[4], g[4], pr[4];
    bool act[4], s[4];

    // phase 1: streaming loads (4 edges); canonical side only (c < r)
#pragma unroll
    for (int i = 0; i < 4; ++i) {
        int e = e0 + i * 256;
        bool p = e < n_edges;
        c[i] = 0; r[i] = -1;
        if (p) { c[i] = col[e]; r[i] = row16[e]; }
        act[i] = p && c[i] < r[i];
    }
    // phase 2: rowptr pairs (random 8B in 160KB, L2-resident)
#pragma unroll
    for (int i = 0; i < 4; ++i) {
        lo[i] = 0; hi[i] = 0;
        if (act[i]) { lo[i] = rowptr[r[i]]; hi[i] = rowptr[r[i] + 1]; }
    }
    // phase 3: interpolation guesses + initial probes
#pragma unroll
    for (int i = 0; i < 4; ++i) {
        s[i] = act[i] && hi[i] > lo[i];
        g[i] = 0; pr[i] = 0;
        if (s[i]) {
            g[i] = lo[i] + (int)((float)c[i] * (float)(hi[i] - lo[i]) * inv_n);
            if (g[i] >= hi[i]) g[i] = hi[i] - 1;
            pr[i] = row16[g[i]];
        }
    }
    // phase 4: local scans; on match (~800 pairs total) exchange through
    // out[] (fp32 exact). Partner is non-canonical -> never writes here;
    // pairs disjoint; edge_value completed -> race-free, deterministic.
#pragma unroll
    for (int i = 0; i < 4; ++i) {
        if (!s[i]) continue;
        int gg = g[i], rv = pr[i], hh = hi[i], ll = lo[i], cc = c[i];
        int match = -1;
        if (rv < cc) {
            while (++gg < hh) { rv = row16[gg]; if (rv >= cc) break; }
            if (gg < hh && rv == cc) match = gg;
        } else {
            while (rv > cc && gg > ll) rv = row16[--gg];
            if (rv == cc) match = gg;
        }
        if (match >= 0) {
            int e = e0 + i * 256;
            float mine   = out[e];        // 0.5 * v_fwd
            float theirs = out[match];    // 0.5 * v_rev
            out[e]     = mine + theirs;
            out[match] = theirs + mine;
        }
    }
}

extern "C" void kernel_launch(void* const* d_in, const int* in_sizes, int n_in,
                              void* d_out, int out_size, void* d_ws, size_t ws_size,
                              hipStream_t stream) {
    const float* embed = (const float*)d_in[0];
    const float* W1    = (const float*)d_in[1];
    const float* b1    = (const float*)d_in[2];
    const float* W2    = (const float*)d_in[3];
    const float* b2    = (const float*)d_in[4];
    const float* noise = (const float*)d_in[5];
    const int*   col   = (const int*)d_in[6];
    const int*   row   = (const int*)d_in[7];

    int n_nodes = in_sizes[0] / 64;   // 40000
    int n_edges = in_sizes[5];        // 1600000
    float* out = (float*)d_out;

    char* ws = (char*)d_ws;
    size_t p_sz   = (size_t)n_nodes * 16 * sizeof(unsigned);   // 2.56 MB each
    size_t e16_sz = (size_t)n_edges * sizeof(unsigned short);  // 3.2 MB
    unsigned*       Ptop   = (unsigned*)ws;
    unsigned*       Pbot   = (unsigned*)(ws + p_sz);
    unsigned short* row16  = (unsigned short*)(ws + 2 * p_sz);
    int*            rowptr = (int*)(ws + 2 * p_sz + e16_sz);

    int gemm_blocks = (n_nodes + 63) / 64;
    int rp_blocks   = (n_nodes + 256) / 256;   // covers v in [0, n_nodes]

    precompute_kernel<<<gemm_blocks, 256, 0, stream>>>(
        embed, W1, b1, Ptop, Pbot, n_nodes);

    edge_value_kernel<<<rp_blocks + (n_edges + 255) / 256, 256, 0, stream>>>(
        (const uint4*)Ptop, (const uint4*)Pbot, W2, b2, noise, col, row,
        row16, out, rowptr, n_edges, n_nodes, rp_blocks);

    symmetrize_kernel<<<(n_edges + 1023) / 1024, 256, 0, stream>>>(
        col, row16, rowptr, out, n_edges, 1.0f / (float)n_nodes);
}